// Round 2
// baseline (1120.344 us; speedup 1.0000x reference)
//
#include <hip/hip_runtime.h>
#include <hip/hip_bf16.h>

// Problem constants
#define BB 64      // batch
#define JJ 2048    // input capsules
#define DI 16      // input dim
#define CC 32      // output capsules
#define OO 32      // output dim
#define CO 1024    // CC*OO
#define TJ 32      // j per block
#define NJT 64     // JJ/TJ
#define NB 4       // b-groups of 16

// One routing pass: recompute u_hat tiles, logits from NPREV stored v's,
// softmax over c (wave-local shuffles), accumulate partial s per j-tile.
// Grid: 256 blocks = 64 j-tiles x 4 b-groups. Block: 256 thr = 4 waves.
// Wave owns 4 b's; lane owns (c = lane&31, o-half = lane>>5) -> 16 (c,o).
template<int NPREV>
__global__ __launch_bounds__(256, 1) void route_pass(
    const float* __restrict__ X, const float* __restrict__ W,
    const float* __restrict__ vprev, float* __restrict__ partial)
{
  const int jt   = blockIdx.x >> 2;
  const int bq   = blockIdx.x & 3;
  const int tid  = threadIdx.x;
  const int wave = tid >> 6;
  const int lane = tid & 63;
  const int c    = lane & 31;
  const int o0   = (lane >> 5) << 4;   // 0 or 16
  const int b0   = bq * 16 + wave * 4;

  float acc[4][16];
#pragma unroll
  for (int bl = 0; bl < 4; ++bl)
#pragma unroll
    for (int ol = 0; ol < 16; ++ol) acc[bl][ol] = 0.f;

  // W[c, j, o, i] flat: ((c*JJ + j)*OO + o)*DI + i  — lane's (c, o0..o0+15, :)
  // is 256 contiguous f32 per j.
  const float* wbase = W + ((size_t)c * JJ * OO + (size_t)o0) * DI;

  for (int jj = 0; jj < TJ; ++jj) {
    const int j = jt * TJ + jj;

    // x[b, j, :16] -> f32 regs for the wave's 4 b's (lane-invariant broadcast loads)
    float xf[4][16];
#pragma unroll
    for (int bl = 0; bl < 4; ++bl) {
      const float4* xp = (const float4*)(X + ((size_t)(b0 + bl) * JJ + j) * DI);
#pragma unroll
      for (int q = 0; q < 4; ++q) {
        float4 x4 = xp[q];
        xf[bl][4*q+0] = x4.x; xf[bl][4*q+1] = x4.y;
        xf[bl][4*q+2] = x4.z; xf[bl][4*q+3] = x4.w;
      }
    }

    const float4* wp = (const float4*)(wbase + (size_t)j * OO * DI);
    float t[4][16];   // u_hat values (only kept when NPREV>0)
#pragma unroll
    for (int ol = 0; ol < 16; ++ol) {
      float wf[16];
#pragma unroll
      for (int q = 0; q < 4; ++q) {
        float4 w4 = wp[4*ol + q];
        wf[4*q+0] = w4.x; wf[4*q+1] = w4.y;
        wf[4*q+2] = w4.z; wf[4*q+3] = w4.w;
      }
#pragma unroll
      for (int bl = 0; bl < 4; ++bl) {
        float tt = 0.f;
#pragma unroll
        for (int i = 0; i < 16; ++i) tt = fmaf(wf[i], xf[bl][i], tt);
        if (NPREV == 0) acc[bl][ol] += tt;   // coef uniform 1/32, scaled at the end
        else            t[bl][ol] = tt;
      }
    }

    if (NPREV > 0) {
#pragma unroll
      for (int bl = 0; bl < 4; ++bl) {
        // logit[b,c,j] = sum_{t<i} v_t[b,c,:] . u_hat[b,c,j,:]
        float dsum = 0.f;
#pragma unroll
        for (int n = 0; n < NPREV; ++n) {
          const float4* vp = (const float4*)(vprev + ((size_t)n * BB + (b0 + bl)) * CO
                                             + c * OO + o0);
#pragma unroll
          for (int q = 0; q < 4; ++q) {
            float4 v4 = vp[q];
            dsum = fmaf(v4.x, t[bl][4*q+0], dsum);
            dsum = fmaf(v4.y, t[bl][4*q+1], dsum);
            dsum = fmaf(v4.z, t[bl][4*q+2], dsum);
            dsum = fmaf(v4.w, t[bl][4*q+3], dsum);
          }
        }
        dsum += __shfl_xor(dsum, 32);           // combine the two o-halves
        // softmax over the 32 c's living in each 32-lane half
        float m = dsum;
#pragma unroll
        for (int s = 16; s >= 1; s >>= 1) m = fmaxf(m, __shfl_xor(m, s));
        float e = __expf(dsum - m);
        float den = e;
#pragma unroll
        for (int s = 16; s >= 1; s >>= 1) den += __shfl_xor(den, s);
        float coef = e / den;
#pragma unroll
        for (int ol = 0; ol < 16; ++ol)
          acc[bl][ol] = fmaf(coef, t[bl][ol], acc[bl][ol]);
      }
    }
  }

  const float cs = (NPREV == 0) ? 0.03125f : 1.f;
#pragma unroll
  for (int bl = 0; bl < 4; ++bl) {
    float* pp = partial + ((size_t)jt * BB + (b0 + bl)) * CO + c * OO + o0;
#pragma unroll
    for (int q = 0; q < 4; ++q) {
      float4 w4 = make_float4(acc[bl][4*q+0]*cs, acc[bl][4*q+1]*cs,
                              acc[bl][4*q+2]*cs, acc[bl][4*q+3]*cs);
      ((float4*)pp)[q] = w4;
    }
  }
}

// Sum the 64 j-tile partials -> s[b,c,o]; squash over o (32 lanes share a (b,c)
// row); write v_i (f32, for the next pass) and optionally the final output.
__global__ __launch_bounds__(256, 1) void reduce_squash(
    const float* __restrict__ partial, float* __restrict__ vout,
    float* __restrict__ out, int last)
{
  const int idx = blockIdx.x * 256 + threadIdx.x;   // = b*CO + c*OO + o
  float s = 0.f;
#pragma unroll 8
  for (int nt = 0; nt < NJT; ++nt) s += partial[(size_t)nt * (BB * CO) + idx];
  float s2 = s * s;
#pragma unroll
  for (int m = 16; m >= 1; m >>= 1) s2 += __shfl_xor(s2, m);
  float scale = s2 / ((1.f + s2) * sqrtf(s2 + 1e-7f));
  float v = scale * s;
  vout[idx] = v;
  if (last) out[idx] = v;
}

extern "C" void kernel_launch(void* const* d_in, const int* in_sizes, int n_in,
                              void* d_out, int out_size, void* d_ws, size_t ws_size,
                              hipStream_t stream) {
  (void)in_sizes; (void)n_in; (void)out_size; (void)ws_size;
  const float* X = (const float*)d_in[0];   // x [64,2048,16] f32
  const float* W = (const float*)d_in[1];   // W [32,2048,32,16] f32
  float* out = (float*)d_out;               // v [64,32,32] f32

  float* partial = (float*)d_ws;                                // 64*64*1024 f32 = 16.8 MB
  float* vbuf    = (float*)((char*)d_ws + (size_t)NJT*BB*CO*4); // 3 * 64*1024 f32

  const int grid = NJT * NB;   // 256

  route_pass<0><<<grid, 256, 0, stream>>>(X, W, nullptr, partial);
  reduce_squash<<<BB*CO/256, 256, 0, stream>>>(partial, vbuf, nullptr, 0);

  route_pass<1><<<grid, 256, 0, stream>>>(X, W, vbuf, partial);
  reduce_squash<<<BB*CO/256, 256, 0, stream>>>(partial, vbuf + BB*CO, nullptr, 0);

  route_pass<2><<<grid, 256, 0, stream>>>(X, W, vbuf, partial);
  reduce_squash<<<BB*CO/256, 256, 0, stream>>>(partial, vbuf + 2*BB*CO, out, 1);
}